// Round 1
// baseline (368.057 us; speedup 1.0000x reference)
//
#include <hip/hip_runtime.h>
#include <math.h>

__device__ __forceinline__ float gelu_f(float x) {
    return 0.5f * x * (1.0f + erff(x * 0.7071067811865476f));
}

// ---------------------------------------------------------------------------
// K1: conv1 (1->16, 3x3, SAME) + maxpool2 + gelu
// x[128,1,128,128] -> h1[128,16,64,64]
// grid 2048 = 128 b * 16 tiles (16x16 pooled tile each)
// ---------------------------------------------------------------------------
__global__ __launch_bounds__(256) void k_conv1(const float* __restrict__ x,
                                               const float* __restrict__ w1,
                                               const float* __restrict__ b1,
                                               float* __restrict__ h1) {
    __shared__ float xs[34][35];
    __shared__ float wS[16][9];
    __shared__ float bS[16];
    const int blk = blockIdx.x;
    const int b = blk >> 4;
    const int tile = blk & 15;
    const int ti = (tile >> 2) << 4, tj = (tile & 3) << 4;
    const int t = threadIdx.x;
    if (t < 144) wS[t / 9][t % 9] = w1[t];
    if (t < 16) bS[t] = b1[t];
    const float* xb = x + b * 16384;
    for (int i = t; i < 34 * 34; i += 256) {
        const int r = i / 34, c = i % 34;
        const int gr = 2 * ti - 1 + r, gc = 2 * tj - 1 + c;
        xs[r][c] = ((unsigned)gr < 128u && (unsigned)gc < 128u) ? xb[gr * 128 + gc] : 0.f;
    }
    __syncthreads();
    const int jj = t & 15, ii = t >> 4;
    float pat[4][4];
#pragma unroll
    for (int r = 0; r < 4; r++)
#pragma unroll
        for (int c = 0; c < 4; c++) pat[r][c] = xs[2 * ii + r][2 * jj + c];
    const int obase = b * 65536 + (ti + ii) * 64 + (tj + jj);
#pragma unroll
    for (int co = 0; co < 16; co++) {
        float w[9];
#pragma unroll
        for (int k = 0; k < 9; k++) w[k] = wS[co][k];
        float s00 = 0.f, s01 = 0.f, s10 = 0.f, s11 = 0.f;
#pragma unroll
        for (int ty = 0; ty < 3; ty++)
#pragma unroll
            for (int tx = 0; tx < 3; tx++) {
                const float wv = w[ty * 3 + tx];
                s00 += wv * pat[ty][tx];
                s01 += wv * pat[ty][tx + 1];
                s10 += wv * pat[ty + 1][tx];
                s11 += wv * pat[ty + 1][tx + 1];
            }
        const float m = fmaxf(fmaxf(s00, s01), fmaxf(s10, s11)) + bS[co];
        h1[obase + co * 4096] = gelu_f(m);
    }
}

// ---------------------------------------------------------------------------
// K2: conv2 (16->32, 3x3, SAME) + maxpool2 (no activation)
// h1[128,16,64,64] -> h[128,32,32,32]
// grid 2048 = 128 b * 16 tiles (8x8 pooled tile each)
// ---------------------------------------------------------------------------
__global__ __launch_bounds__(256) void k_conv2(const float* __restrict__ h1,
                                               const float* __restrict__ w2,
                                               const float* __restrict__ b2,
                                               float* __restrict__ h) {
    __shared__ float hs[16][18][19];
    __shared__ float wS[32][145];
    __shared__ float bS[32];
    const int blk = blockIdx.x;
    const int b = blk >> 4;
    const int tile = blk & 15;
    const int ti = (tile >> 2) << 3, tj = (tile & 3) << 3;
    const int t = threadIdx.x;
    for (int i = t; i < 32 * 144; i += 256) wS[i / 144][i % 144] = w2[i];
    if (t < 32) bS[t] = b2[t];
    const float* h1b = h1 + b * 65536;
    for (int i = t; i < 16 * 324; i += 256) {
        const int ci = i / 324, rc = i % 324, r = rc / 18, c = rc % 18;
        const int gr = 2 * ti - 1 + r, gc = 2 * tj - 1 + c;
        hs[ci][r][c] = ((unsigned)gr < 64u && (unsigned)gc < 64u) ? h1b[ci * 4096 + gr * 64 + gc] : 0.f;
    }
    __syncthreads();
    const int co = t >> 3, irow = t & 7;
    float acc0[8], acc1[8], acc2[8], acc3[8];
#pragma unroll
    for (int j = 0; j < 8; j++) { acc0[j] = 0.f; acc1[j] = 0.f; acc2[j] = 0.f; acc3[j] = 0.f; }
#pragma unroll 1
    for (int ci = 0; ci < 16; ci++) {
        float w[9];
#pragma unroll
        for (int k = 0; k < 9; k++) w[k] = wS[co][ci * 9 + k];
        float pat[4][4];
#pragma unroll
        for (int r = 0; r < 4; r++)
#pragma unroll
            for (int c = 0; c < 4; c++) pat[r][c] = hs[ci][2 * irow + r][c];
#pragma unroll
        for (int j = 0; j < 8; j++) {
#pragma unroll
            for (int ty = 0; ty < 3; ty++)
#pragma unroll
                for (int tx = 0; tx < 3; tx++) {
                    const float wv = w[ty * 3 + tx];
                    acc0[j] += wv * pat[ty][tx];
                    acc1[j] += wv * pat[ty][tx + 1];
                    acc2[j] += wv * pat[ty + 1][tx];
                    acc3[j] += wv * pat[ty + 1][tx + 1];
                }
            if (j < 7) {
#pragma unroll
                for (int r = 0; r < 4; r++) {
                    pat[r][0] = pat[r][2]; pat[r][1] = pat[r][3];
                    pat[r][2] = hs[ci][2 * irow + r][2 * j + 4];
                    pat[r][3] = hs[ci][2 * irow + r][2 * j + 5];
                }
            }
        }
    }
    float* hb = h + (b * 32 + co) * 1024 + (ti + irow) * 32 + tj;
#pragma unroll
    for (int j = 0; j < 8; j++) {
        hb[j] = fmaxf(fmaxf(acc0[j], acc1[j]), fmaxf(acc2[j], acc3[j])) + bS[co];
    }
}

// ---------------------------------------------------------------------------
// K3: VectorQuantize: per n argmin_k ||z_n - cb_k||^2, idx as float, loss partials.
// h[128,32,32,32] viewed as z[b][n=1024][c=32] with z[c] = h[b][c][n].
// grid 512 = 128 b * 4 chunks (256 n each), 256 thr (4 waves * 64 n)
// LDS: cbS[32][256] (half of codebook, [c][k]) + zsS[32][256] = exactly 64KB.
// ---------------------------------------------------------------------------
__global__ __launch_bounds__(256) void k_vq(const float* __restrict__ h,
                                            const float* __restrict__ cb,
                                            float* __restrict__ idx_out,
                                            float* __restrict__ partials) {
    __shared__ float cbS[32][256];
    __shared__ float zsS[32][256];
    const int blk = blockIdx.x;
    const int b = blk >> 2, chunk = blk & 3;
    const int t = threadIdx.x, lane = t & 63, wave = t >> 6;
    const int nbase = chunk * 256;
    const float* hb = h + b * 32768;
    for (int i = t; i < 8192; i += 256) {
        const int c = i >> 8, n = i & 255;
        zsS[c][n] = hb[c * 1024 + nbase + n];
    }
    float st_d = 3.4e38f;
    int st_k = 0;
#pragma unroll 1
    for (int pass = 0; pass < 2; pass++) {
        __syncthreads();
        for (int i = t; i < 8192; i += 256) {
            cbS[i & 31][i >> 5] = cb[pass * 8192 + i];
        }
        __syncthreads();
        // this lane's 4 codes: k_half = lane*4 + j  (global k = pass*256 + k_half)
        float cc[4] = {0.f, 0.f, 0.f, 0.f};
#pragma unroll 4
        for (int c = 0; c < 32; c++) {
            const float4 v = *(const float4*)&cbS[c][lane * 4];
            cc[0] += v.x * v.x; cc[1] += v.y * v.y; cc[2] += v.z * v.z; cc[3] += v.w * v.w;
        }
#pragma unroll 1
        for (int g = 0; g < 8; g++) {
            const int n0 = wave * 64 + g * 8;
            float dot[8][4];
            float zz[8];
#pragma unroll
            for (int nn = 0; nn < 8; nn++) {
                zz[nn] = 0.f;
                dot[nn][0] = 0.f; dot[nn][1] = 0.f; dot[nn][2] = 0.f; dot[nn][3] = 0.f;
            }
#pragma unroll 4
            for (int c = 0; c < 32; c++) {
                const float4 v = *(const float4*)&cbS[c][lane * 4];
                const float4 za = *(const float4*)&zsS[c][n0];
                const float4 zb = *(const float4*)&zsS[c][n0 + 4];
                const float zv[8] = {za.x, za.y, za.z, za.w, zb.x, zb.y, zb.z, zb.w};
#pragma unroll
                for (int nn = 0; nn < 8; nn++) {
                    zz[nn] += zv[nn] * zv[nn];
                    dot[nn][0] += zv[nn] * v.x;
                    dot[nn][1] += zv[nn] * v.y;
                    dot[nn][2] += zv[nn] * v.z;
                    dot[nn][3] += zv[nn] * v.w;
                }
            }
#pragma unroll
            for (int nn = 0; nn < 8; nn++) {
                const float d0 = (zz[nn] - 2.f * dot[nn][0]) + cc[0];
                const float d1 = (zz[nn] - 2.f * dot[nn][1]) + cc[1];
                const float d2 = (zz[nn] - 2.f * dot[nn][2]) + cc[2];
                const float d3 = (zz[nn] - 2.f * dot[nn][3]) + cc[3];
                float dl = d0; int kl = lane * 4;
                if (d1 < dl) { dl = d1; kl = lane * 4 + 1; }
                if (d2 < dl) { dl = d2; kl = lane * 4 + 2; }
                if (d3 < dl) { dl = d3; kl = lane * 4 + 3; }
#pragma unroll
                for (int m = 1; m < 64; m <<= 1) {
                    const float od = __shfl_xor(dl, m, 64);
                    const int ok = __shfl_xor(kl, m, 64);
                    if (od < dl || (od == dl && ok < kl)) { dl = od; kl = ok; }
                }
                const int kg = pass * 256 + kl;
                if (lane == g * 8 + nn) {
                    if (dl < st_d) { st_d = dl; st_k = kg; }   // strict <: keeps lower-k pass on tie
                }
            }
        }
    }
    idx_out[b * 1024 + nbase + wave * 64 + lane] = (float)st_k;
    float s = st_d;
#pragma unroll
    for (int m = 1; m < 64; m <<= 1) s += __shfl_xor(s, m, 64);
    if (lane == 0) partials[blk * 4 + wave] = s;
}

// ---------------------------------------------------------------------------
// K4: conv3 (32->16, 3x3, SAME) on nearest-2x-upsampled h, + gelu.
// Upsample folded: per output parity the 3x3 collapses to 2x2 effective taps on h.
// h[128,32,32,32] -> g[128,16,64,64]
// grid 512 = 128 b * 4 strips (16 out rows). thread: co = t&15, out row p = p0 + (t>>4).
// ---------------------------------------------------------------------------
__global__ __launch_bounds__(256) void k_conv3(const float* __restrict__ h,
                                               const float* __restrict__ w3,
                                               const float* __restrict__ b3,
                                               float* __restrict__ g) {
    __shared__ float hS[32][10][34];   // [ci][h rows i0-1..i0+8][h cols -1..32]
    __shared__ float wS[16][289];
    __shared__ float bS[16];
    const int blk = blockIdx.x;
    const int b = blk >> 2, strip = blk & 3;
    const int p0 = strip * 16, i0 = strip * 8;
    const int t = threadIdx.x;
    for (int i = t; i < 16 * 288; i += 256) wS[i / 288][i % 288] = w3[i];
    if (t < 16) bS[t] = b3[t];
    const float* hb = h + b * 32768;
    for (int i = t; i < 32 * 340; i += 256) {
        const int ci = i / 340, rc = i % 340, r = rc / 34, c = rc % 34;
        const int gr = i0 - 1 + r, gc = c - 1;
        hS[ci][r][c] = ((unsigned)gr < 32u && (unsigned)gc < 32u) ? hb[ci * 1024 + gr * 32 + gc] : 0.f;
    }
    __syncthreads();
    const int co = t & 15, rowid = t >> 4;
    const int p = p0 + rowid;
    const int pe = p & 1;
    const int iq = p >> 1;
    const int lrA = (pe ? iq : iq - 1) - (i0 - 1);
    float acc[64];
#pragma unroll
    for (int q = 0; q < 64; q++) acc[q] = 0.f;
#pragma unroll 1
    for (int ci = 0; ci < 32; ci++) {
        float w[9];
#pragma unroll
        for (int k = 0; k < 9; k++) w[k] = wS[co][ci * 9 + k];
        // row-combined weights: row A = (pe? i : i-1), row B = A+1
        const float rA0 = pe ? (w[0] + w[3]) : w[0];
        const float rA1 = pe ? (w[1] + w[4]) : w[1];
        const float rA2 = pe ? (w[2] + w[5]) : w[2];
        const float rB0 = pe ? w[6] : (w[3] + w[6]);
        const float rB1 = pe ? w[7] : (w[4] + w[7]);
        const float rB2 = pe ? w[8] : (w[5] + w[8]);
        // col-combined: even q -> cols {j-1, j}; odd q -> cols {j, j+1}
        const float we_a0 = rA0, we_a1 = rA1 + rA2;
        const float we_b0 = rB0, we_b1 = rB1 + rB2;
        const float wo_a0 = rA0 + rA1, wo_a1 = rA2;
        const float wo_b0 = rB0 + rB1, wo_b1 = rB2;
        const float* hA = &hS[ci][lrA][0];
        const float* hB = &hS[ci][lrA + 1][0];
        float a0 = hA[0], a1 = hA[1];
        float c0 = hB[0], c1 = hB[1];
#pragma unroll
        for (int j = 0; j < 32; j++) {
            const float a2 = hA[j + 2];
            const float c2 = hB[j + 2];
            acc[2 * j]     += we_a0 * a0 + we_a1 * a1 + we_b0 * c0 + we_b1 * c1;
            acc[2 * j + 1] += wo_a0 * a1 + wo_a1 * a2 + wo_b0 * c1 + wo_b1 * c2;
            a0 = a1; a1 = a2; c0 = c1; c1 = c2;
        }
    }
    const float bias = bS[co];
    float4* g4 = (float4*)(g + (b * 16 + co) * 4096 + p * 64);
#pragma unroll
    for (int q4 = 0; q4 < 16; q4++) {
        float4 v;
        v.x = gelu_f(acc[4 * q4 + 0] + bias);
        v.y = gelu_f(acc[4 * q4 + 1] + bias);
        v.z = gelu_f(acc[4 * q4 + 2] + bias);
        v.w = gelu_f(acc[4 * q4 + 3] + bias);
        g4[q4] = v;
    }
}

// ---------------------------------------------------------------------------
// K5: conv4 (16->1, 3x3, SAME) on nearest-2x-upsampled g, + clip [-1,1].
// g[128,16,64,64] -> out[128,1,128,128]
// grid 1024 = 128 b * 8 strips (16 out rows). thread: row p = p0 + (t>>4), col group t&15.
// ---------------------------------------------------------------------------
__global__ __launch_bounds__(256) void k_conv4(const float* __restrict__ g,
                                               const float* __restrict__ w4,
                                               const float* __restrict__ b4,
                                               float* __restrict__ out) {
    __shared__ float gS[16][10][66];
    __shared__ float wS[16][9];
    const int blk = blockIdx.x;
    const int b = blk >> 3, strip = blk & 7;
    const int p0 = strip * 16, i0 = strip * 8;
    const int t = threadIdx.x;
    if (t < 144) wS[t / 9][t % 9] = w4[t];
    const float* gb = g + b * 65536;
    for (int i = t; i < 16 * 660; i += 256) {
        const int ci = i / 660, rc = i % 660, r = rc / 66, c = rc % 66;
        const int gr = i0 - 1 + r, gc = c - 1;
        gS[ci][r][c] = ((unsigned)gr < 64u && (unsigned)gc < 64u) ? gb[ci * 4096 + gr * 64 + gc] : 0.f;
    }
    __syncthreads();
    const int rowid = t >> 4, cg = t & 15;
    const int p = p0 + rowid;
    const int pe = p & 1;
    const int iq = p >> 1;
    const int lrA = (pe ? iq : iq - 1) - (i0 - 1);
    float acc[8];
#pragma unroll
    for (int q = 0; q < 8; q++) acc[q] = 0.f;
#pragma unroll 1
    for (int ci = 0; ci < 16; ci++) {
        float w[9];
#pragma unroll
        for (int k = 0; k < 9; k++) w[k] = wS[ci][k];
        const float rA0 = pe ? (w[0] + w[3]) : w[0];
        const float rA1 = pe ? (w[1] + w[4]) : w[1];
        const float rA2 = pe ? (w[2] + w[5]) : w[2];
        const float rB0 = pe ? w[6] : (w[3] + w[6]);
        const float rB1 = pe ? w[7] : (w[4] + w[7]);
        const float rB2 = pe ? w[8] : (w[5] + w[8]);
        const float we_a0 = rA0, we_a1 = rA1 + rA2;
        const float we_b0 = rB0, we_b1 = rB1 + rB2;
        const float wo_a0 = rA0 + rA1, wo_a1 = rA2;
        const float wo_b0 = rB0 + rB1, wo_b1 = rB2;
        const float* hA = &gS[ci][lrA][4 * cg];
        const float* hB = &gS[ci][lrA + 1][4 * cg];
        float a0 = hA[0], a1 = hA[1];
        float c0 = hB[0], c1 = hB[1];
#pragma unroll
        for (int j = 0; j < 4; j++) {
            const float a2 = hA[j + 2];
            const float c2 = hB[j + 2];
            acc[2 * j]     += we_a0 * a0 + we_a1 * a1 + we_b0 * c0 + we_b1 * c1;
            acc[2 * j + 1] += wo_a0 * a1 + wo_a1 * a2 + wo_b0 * c1 + wo_b1 * c2;
            a0 = a1; a1 = a2; c0 = c1; c1 = c2;
        }
    }
    const float bias = b4[0];
    float* ob = out + b * 16384 + p * 128 + 8 * cg;
#pragma unroll
    for (int q = 0; q < 8; q++) ob[q] = fminf(fmaxf(acc[q] + bias, -1.f), 1.f);
}

// ---------------------------------------------------------------------------
// K6: deterministic loss reduction: mean over B*N*C = 4194304 elements
// ---------------------------------------------------------------------------
__global__ __launch_bounds__(256) void k_reduce(const float* __restrict__ partials,
                                                float* __restrict__ loss) {
    __shared__ float red[256];
    const int t = threadIdx.x;
    float s = 0.f;
    for (int i = t; i < 2048; i += 256) s += partials[i];
    red[t] = s;
    __syncthreads();
    for (int off = 128; off > 0; off >>= 1) {
        if (t < off) red[t] += red[t + off];
        __syncthreads();
    }
    if (t == 0) loss[0] = red[0] * (1.0f / 4194304.0f);
}

extern "C" void kernel_launch(void* const* d_in, const int* in_sizes, int n_in,
                              void* d_out, int out_size, void* d_ws, size_t ws_size,
                              hipStream_t stream) {
    const float* x  = (const float*)d_in[0];
    const float* w1 = (const float*)d_in[1];
    const float* b1 = (const float*)d_in[2];
    const float* w2 = (const float*)d_in[3];
    const float* b2 = (const float*)d_in[4];
    const float* cb = (const float*)d_in[5];
    const float* w3 = (const float*)d_in[6];
    const float* b3 = (const float*)d_in[7];
    const float* w4 = (const float*)d_in[8];
    const float* b4 = (const float*)d_in[9];

    float* ws = (float*)d_ws;
    float* h1 = ws;                  // 8388608 floats [128,16,64,64]; reused as g after conv2
    float* h  = ws + 8388608;        // 4194304 floats [128,32,32,32]
    float* g  = h1;                  // alias: h1 is dead after k_conv2
    float* pa = ws + 12582912;       // 2048 floats (per-wave loss partials)
    float* outp = (float*)d_out;     // [out 2097152][idx 131072][loss 1]

    k_conv1<<<2048, 256, 0, stream>>>(x, w1, b1, h1);
    k_conv2<<<2048, 256, 0, stream>>>(h1, w2, b2, h);
    k_vq<<<512, 256, 0, stream>>>(h, cb, outp + 2097152, pa);
    k_conv3<<<512, 256, 0, stream>>>(h, w3, b3, g);
    k_conv4<<<1024, 256, 0, stream>>>(g, w4, b4, outp);
    k_reduce<<<1, 256, 0, stream>>>(pa, outp + 2228224);
}